// Round 15
// baseline (201.390 us; speedup 1.0000x reference)
//
#include <hip/hip_runtime.h>
#include <hip/hip_bf16.h>

#define NEG_SLOPE 0.2f
#define NBMAX 320       // max buckets: 3N/512; N=50000 -> 293
#define KB    512       // keys per bucket
#define CAP   10240     // fixed staging capacity per bucket (mean 8192, sigma~90)
#define CHUNK 4096      // edges per stage block (LDS-cached)
#define XCB   1024      // x-convert blocks appended to K1

typedef short bf16x8 __attribute__((ext_vector_type(8)));
typedef float f32x16 __attribute__((ext_vector_type(16)));

__device__ inline ushort f2bf(float f) {
  __hip_bfloat16 b = __float2bfloat16(f);
  return *(ushort*)&b;
}

// ---------- edge decode helper ----------
__device__ inline void edge_decode(int i, int E0, int E1,
                                   const int* __restrict__ s0, const int* __restrict__ d0,
                                   const int* __restrict__ s1, const int* __restrict__ d1,
                                   const int* __restrict__ s2, const int* __restrict__ d2,
                                   int N, int& src, int& key) {
  if (i < E0)            { src = s0[i];            key = d0[i]; }
  else if (i < E0 + E1)  { src = s1[i - E0];       key = N + d1[i - E0]; }
  else                   { src = s2[i - E0 - E1];  key = 2 * N + d2[i - E0 - E1]; }
}

// ---------- K1: stage (< SB) || prep WbigT (SB..SB+447) || x->bf16 (rest) ----
struct StageSmem {
  ushort es_src[CHUNK];
  int    es_key[CHUNK];
  int    lh[NBMAX];
  int    lb[NBMAX];
};

__global__ __launch_bounds__(256, 2)
void stage_prep_kernel(const int* __restrict__ s0, const int* __restrict__ d0,
                       const int* __restrict__ s1, const int* __restrict__ d1,
                       const int* __restrict__ s2, const int* __restrict__ d2,
                       int E0, int E1, int E2,
                       int* __restrict__ bcnt, unsigned* __restrict__ staging,
                       int N, int NB, int SB,
                       const float* __restrict__ W,
                       const float* __restrict__ a_src,
                       const float* __restrict__ a_dst,
                       ushort* __restrict__ WbigT,
                       const float* __restrict__ x, ushort* __restrict__ xbf) {
  __shared__ __align__(16) char smem_raw[sizeof(StageSmem)];
  const int t = threadIdx.x;
  if (blockIdx.x >= SB + 448) {
    // ---- x -> bf16 convert body (grid-stride, 8 floats/thread/iter) ----
    const int xb = blockIdx.x - SB - 448;
    const size_t total = (size_t)N * 32;   // groups of 8 floats
    for (size_t g = (size_t)xb * 256 + t; g < total; g += (size_t)XCB * 256) {
      const float* xp = x + g * 8;
      float4 v0 = *(const float4*)xp;
      float4 v1 = *(const float4*)(xp + 4);
      uint4 pk;
      pk.x = (unsigned)f2bf(v0.x) | ((unsigned)f2bf(v0.y) << 16);
      pk.y = (unsigned)f2bf(v0.z) | ((unsigned)f2bf(v0.w) << 16);
      pk.z = (unsigned)f2bf(v1.x) | ((unsigned)f2bf(v1.y) << 16);
      pk.w = (unsigned)f2bf(v1.z) | ((unsigned)f2bf(v1.w) << 16);
      *(uint4*)(xbf + g * 8) = pk;
    }
    return;
  }
  if (blockIdx.x >= SB) {
    // ---- prep body ----
    int i = (blockIdx.x - SB) * 256 + t;   // over 448*256
    int c = i >> 8, k = i & 255;
    float v = 0.f;
    if (c < 384) {
      int r = c >> 7, j = c & 127;
      v = W[((size_t)r * 256 + k) * 128 + j];
    } else if (c < 408) {
      int c6 = c - 384, r = c6 >> 3, hh = c6 & 7, hd = hh & 3;
      const float* a = (hh < 4 ? a_src : a_dst) + (r * 4 + hd) * 32;
      const float* wp = W + ((size_t)r * 256 + k) * 128 + hd * 32;
#pragma unroll
      for (int d = 0; d < 32; ++d) v += wp[d] * a[d];
    }
    WbigT[i] = f2bf(v);
    return;
  }
  // ---- stage body ----
  StageSmem& sm = *reinterpret_cast<StageSmem*>(smem_raw);
  for (int k = t; k < NB; k += 256) sm.lh[k] = 0;
  __syncthreads();
  const int Etot = E0 + E1 + E2;
  const int lo = blockIdx.x * CHUNK;
  const int hi = min(lo + CHUNK, Etot);
  const int n = hi - lo;
  for (int i = t; i < n; i += 256) {
    int src, key;
    edge_decode(lo + i, E0, E1, s0, d0, s1, d1, s2, d2, N, src, key);
    sm.es_src[i] = (ushort)src;
    sm.es_key[i] = key;
    atomicAdd(&sm.lh[key >> 9], 1);
  }
  __syncthreads();
  for (int k = t; k < NB; k += 256) {
    int v = sm.lh[k];
    sm.lb[k] = v ? (k * CAP + atomicAdd(&bcnt[k], v)) : 0;
    sm.lh[k] = 0;
  }
  __syncthreads();
  for (int i = t; i < n; i += 256) {
    int key = sm.es_key[i];
    int b = key >> 9;
    int pos = sm.lb[b] + atomicAdd(&sm.lh[b], 1);
    if (pos < (b + 1) * CAP)   // overflow guard (never hit for uniform dst)
      staging[pos] = ((unsigned)(key & 511) << 16) | (unsigned)sm.es_src[i];
  }
}

// ---------- K2: sort (blocks < NB) || gemm (blocks >= NB) --------------------
// gemm now reads pre-converted bf16 x (half the bytes, no cvt in A-stage)
struct GemmSmem {
  ushort As[64][40];
  ushort Bs[448][40];
};
struct SortSmem {
  unsigned es[CAP];      // 40KB bucket slice
  int cnt[KB];
  int cur[KB];
  int wsum[4];
};

__global__ __launch_bounds__(256, 2)
void sort_gemm_kernel(const unsigned* __restrict__ staging, const int* __restrict__ bcnt,
                      int* __restrict__ offs, int* __restrict__ ends,
                      ushort* __restrict__ srt, int n3, int NB,
                      const ushort* __restrict__ xbf, const ushort* __restrict__ WT,
                      ushort* __restrict__ hall, float* __restrict__ al, int M) {
  __shared__ __align__(16) char smem_raw[sizeof(SortSmem) > sizeof(GemmSmem)
                                             ? sizeof(SortSmem) : sizeof(GemmSmem)];
  const int t = threadIdx.x;

  if (blockIdx.x < NB) {
    // ================= SORT body =================
    SortSmem& sm = *reinterpret_cast<SortSmem*>(smem_raw);
    const int b = blockIdx.x;
    const int base = b * KB;
    const int lo = b * CAP;
    const int m = min(bcnt[b], CAP);
    sm.cnt[t] = 0;
    sm.cnt[t + 256] = 0;
    __syncthreads();
    for (int i = t; i < m; i += 256) {
      unsigned p = staging[lo + i];
      sm.es[i] = p;
      atomicAdd(&sm.cnt[p >> 16], 1);
    }
    __syncthreads();
    const int lane = t & 63, wid = t >> 6;
    int c0 = sm.cnt[2 * t], c1 = sm.cnt[2 * t + 1];
    int v = c0 + c1;
    int sv = v;
#pragma unroll
    for (int d = 1; d < 64; d <<= 1) {
      int u = __shfl_up(sv, d);
      if (lane >= d) sv += u;
    }
    if (lane == 63) sm.wsum[wid] = sv;
    __syncthreads();
    if (t < 4) {
      int ws = sm.wsum[t];
#pragma unroll
      for (int d = 1; d < 4; d <<= 1) {
        int u = __shfl_up(ws, d);
        if (t >= d) ws += u;
      }
      sm.wsum[t] = ws;
    }
    __syncthreads();
    int excl = (wid ? sm.wsum[wid - 1] : 0) + sv - v;
    int st0 = lo + excl;
    int st1 = st0 + c0;
    sm.cur[2 * t] = st0;
    sm.cur[2 * t + 1] = st1;
    if (base + 2 * t < n3) {
      offs[base + 2 * t] = st0;
      ends[base + 2 * t] = st0 + c0;
    }
    if (base + 2 * t + 1 < n3) {
      offs[base + 2 * t + 1] = st1;
      ends[base + 2 * t + 1] = st1 + c1;
    }
    __syncthreads();
    for (int i = t; i < m; i += 256) {
      unsigned p = sm.es[i];
      int pos = atomicAdd(&sm.cur[p >> 16], 1);
      srt[pos] = (ushort)(p & 0xffffu);
    }
  } else {
    // ================= GEMM body =================
    GemmSmem& sm = *reinterpret_cast<GemmSmem*>(smem_raw);
    const int bm = (blockIdx.x - NB) * 64;
    const int l = t & 63;
    const int w = t >> 6;
    const int wm = (w >> 1) * 32;
    const int wn = (w & 1) * 224;
    const int lr31 = l & 31;
    const int kg = (l >> 5) * 8;

    f32x16 acc[7];
#pragma unroll
    for (int j = 0; j < 7; ++j)
#pragma unroll
      for (int r = 0; r < 16; ++r) acc[j][r] = 0.f;

    for (int k0 = 0; k0 < 256; k0 += 32) {
      {
        // A-stage: bf16 x, one uint4 (8 bf16) per thread, 2 threads/row-chunk
        int row = t >> 2, seg = t & 3;
        int grow = bm + row;
        uint4 pk = make_uint4(0u, 0u, 0u, 0u);
        if (grow < M)
          pk = *(const uint4*)(xbf + (size_t)grow * 256 + k0 + seg * 8);
        *(uint4*)&sm.As[row][seg * 8] = pk;
      }
#pragma unroll
      for (int p = 0; p < 7; ++p) {
        int idx = p * 256 + t;
        int nrow = idx >> 2, ch = idx & 3;
        *(uint4*)&sm.Bs[nrow][ch * 8] =
            *(const uint4*)(WT + (size_t)nrow * 256 + k0 + ch * 8);
      }
      __syncthreads();
#pragma unroll
      for (int kk = 0; kk < 32; kk += 16) {
        bf16x8 af = *(bf16x8*)&sm.As[wm + lr31][kk + kg];
#pragma unroll
        for (int j = 0; j < 7; ++j) {
          bf16x8 bf = *(bf16x8*)&sm.Bs[wn + j * 32 + lr31][kk + kg];
          acc[j] = __builtin_amdgcn_mfma_f32_32x32x16_bf16(af, bf, acc[j], 0, 0, 0);
        }
      }
      __syncthreads();
    }

#pragma unroll
    for (int j = 0; j < 7; ++j) {
      int gcol = wn + j * 32 + lr31;
#pragma unroll
      for (int r = 0; r < 16; ++r) {
        int grow = bm + wm + (l >> 5) * 4 + (r & 3) + 8 * (r >> 2);
        if (grow >= M) continue;
        float c = acc[j][r];
        if (gcol < 384) {
          int rel = gcol >> 7, jj = gcol & 127;
          hall[((size_t)rel * M + grow) * 128 + jj] = f2bf(c);
        } else if (gcol < 408) {
          int c6 = gcol - 384, rr = c6 >> 3, hh = c6 & 7;
          al[(((size_t)(hh < 4 ? 0 : 3) + rr) * M + grow) * 4 + (hh & 3)] = c;
        }
      }
    }
  }
}

// ---------- K3: fused softmax+gather, 4 edges x 16 feature-lanes per wave ----
__global__ __launch_bounds__(128)
void gat_fused_kernel(const ushort* __restrict__ srt, const int* __restrict__ offs,
                      const int* __restrict__ ends,
                      const ushort* __restrict__ hall,
                      const float* __restrict__ al,
                      const float* __restrict__ bias,
                      float* __restrict__ out, int N) {
  const int d = blockIdx.x;
  const int t = threadIdx.x;
  const int w = t >> 6;       // wave 0/1
  const int l = t & 63;
  const int eg = l >> 4;      // edge slot 0..3
  const int fl = l & 15;      // feature slot
  const int h = fl >> 2;      // head

  __shared__ float slab[3][2][16][9];   // rel, wave, fl, {r0..r7, dl}

#pragma unroll
  for (int rel = 0; rel < 3; ++rel) {
    const int key = rel * N + d;
    const int start = offs[key];
    const int dend = ends[key];
    const float* alS = al + (size_t)rel * N * 4;
    const ushort* hrel = hall + (size_t)rel * N * 128;
    const float ald = al[((size_t)(3 + rel) * N + d) * 4 + h];
    float r0 = 0.f, r1 = 0.f, r2 = 0.f, r3 = 0.f;
    float r4 = 0.f, r5 = 0.f, r6 = 0.f, r7 = 0.f;
    float dl = 0.f;
#pragma unroll 2
    for (int e = start + w * 4 + eg; e < dend; e += 8) {
      int s = srt[e];
      float a = alS[(size_t)s * 4 + h] + ald;
      a = fmaxf(a, NEG_SLOPE * a);     // leaky relu
      float ex = __expf(a);
      dl += ex;
      uint4 u = *(const uint4*)(hrel + (size_t)s * 128 + fl * 8);
      r0 += __uint_as_float(u.x << 16) * ex;
      r1 += __uint_as_float(u.x & 0xffff0000u) * ex;
      r2 += __uint_as_float(u.y << 16) * ex;
      r3 += __uint_as_float(u.y & 0xffff0000u) * ex;
      r4 += __uint_as_float(u.z << 16) * ex;
      r5 += __uint_as_float(u.z & 0xffff0000u) * ex;
      r6 += __uint_as_float(u.w << 16) * ex;
      r7 += __uint_as_float(u.w & 0xffff0000u) * ex;
    }
    r0 += __shfl_xor(r0, 16); r0 += __shfl_xor(r0, 32);
    r1 += __shfl_xor(r1, 16); r1 += __shfl_xor(r1, 32);
    r2 += __shfl_xor(r2, 16); r2 += __shfl_xor(r2, 32);
    r3 += __shfl_xor(r3, 16); r3 += __shfl_xor(r3, 32);
    r4 += __shfl_xor(r4, 16); r4 += __shfl_xor(r4, 32);
    r5 += __shfl_xor(r5, 16); r5 += __shfl_xor(r5, 32);
    r6 += __shfl_xor(r6, 16); r6 += __shfl_xor(r6, 32);
    r7 += __shfl_xor(r7, 16); r7 += __shfl_xor(r7, 32);
    dl += __shfl_xor(dl, 16); dl += __shfl_xor(dl, 32);
    if (l < 16) {
      slab[rel][w][fl][0] = r0; slab[rel][w][fl][1] = r1;
      slab[rel][w][fl][2] = r2; slab[rel][w][fl][3] = r3;
      slab[rel][w][fl][4] = r4; slab[rel][w][fl][5] = r5;
      slab[rel][w][fl][6] = r6; slab[rel][w][fl][7] = r7;
      slab[rel][w][fl][8] = dl;
    }
  }
  __syncthreads();
  {
    int fl2 = t >> 3, k = t & 7;
    int f = fl2 * 8 + k;
    float o = bias[f] + bias[128 + f] + bias[256 + f];
#pragma unroll
    for (int rel = 0; rel < 3; ++rel) {
      float D = slab[rel][0][fl2][8] + slab[rel][1][fl2][8];
      float R = slab[rel][0][fl2][k] + slab[rel][1][fl2][k];
      o += R / (D + 1e-16f);
    }
    out[(size_t)d * 128 + f] = o;
  }
}

extern "C" void kernel_launch(void* const* d_in, const int* in_sizes, int n_in,
                              void* d_out, int out_size, void* d_ws, size_t ws_size,
                              hipStream_t stream) {
  const float* x     = (const float*)d_in[0];
  const int*   ei[3] = {(const int*)d_in[1], (const int*)d_in[2], (const int*)d_in[3]};
  const float* W     = (const float*)d_in[4];
  const float* a_src = (const float*)d_in[5];
  const float* a_dst = (const float*)d_in[6];
  const float* bias  = (const float*)d_in[7];

  const int Fin = 256;
  const int N = in_sizes[0] / Fin;
  const int E0 = in_sizes[1] / 2, E1 = in_sizes[2] / 2, E2 = in_sizes[3] / 2;
  const int Etot = E0 + E1 + E2;
  const int n3 = 3 * N;
  const int NB = (n3 + KB - 1) / KB;          // 512-key buckets
  const int GB = (N + 63) / 64;               // gemm blocks
  const int SB = (Etot + CHUNK - 1) / CHUNK;  // stage blocks

  float* out = (float*)d_out;

  // ws layout
  char* p = (char*)d_ws;
  ushort*   WbigT   = (ushort*)p;    p += (size_t)448 * 256 * 2;
  ushort*   xbf     = (ushort*)p;    p += (size_t)N * 256 * 2;
  ushort*   hall    = (ushort*)p;    p += (size_t)N * 384 * 2;
  float*    al      = (float*)p;     p += (size_t)6 * N * 4 * 4;
  unsigned* staging = (unsigned*)p;  p += (size_t)NB * CAP * 4;
  ushort*   srt     = (ushort*)p;    p += (size_t)NB * CAP * 2;
  int*      offs    = (int*)p;       p += (size_t)n3 * 4;
  int*      ends    = (int*)p;       p += (size_t)n3 * 4;
  int*      bcnt    = (int*)p;       p += NBMAX * 4;

  // zero bucket counters
  hipMemsetAsync(bcnt, 0, NBMAX * sizeof(int), stream);

  // K1: stage (long pole, blocks first) || prep WbigT || x->bf16
  stage_prep_kernel<<<SB + 448 + XCB, 256, 0, stream>>>(
      ei[0], ei[0] + E0, ei[1], ei[1] + E1, ei[2], ei[2] + E2,
      E0, E1, E2, bcnt, staging, N, NB, SB,
      W, a_src, a_dst, WbigT, x, xbf);

  // K2: sort (blocks first, overlaps gemm bulk) || gemm (bf16 x)
  sort_gemm_kernel<<<NB + GB, 256, 0, stream>>>(
      staging, bcnt, offs, ends, srt, n3, NB,
      xbf, WbigT, hall, al, N);

  // K3: fused softmax + gather + bias, one block per dst row
  gat_fused_kernel<<<N, 128, 0, stream>>>(srt, offs, ends, hall, al, bias, out, N);
}

// Round 16
// 199.037 us; speedup vs baseline: 1.0118x; 1.0118x over previous
//
#include <hip/hip_runtime.h>
#include <hip/hip_bf16.h>

#define NEG_SLOPE 0.2f
#define NBMAX 320       // max buckets: 3N/512; N=50000 -> 293
#define KB    512       // keys per bucket
#define CAP   10240     // fixed staging capacity per bucket (mean 8192, sigma~90)
#define CHUNK 4096      // edges per stage block (LDS-cached)

typedef short bf16x8 __attribute__((ext_vector_type(8)));
typedef float f32x16 __attribute__((ext_vector_type(16)));

__device__ inline ushort f2bf(float f) {
  __hip_bfloat16 b = __float2bfloat16(f);
  return *(ushort*)&b;
}

// ---------- edge decode helper ----------
__device__ inline void edge_decode(int i, int E0, int E1,
                                   const int* __restrict__ s0, const int* __restrict__ d0,
                                   const int* __restrict__ s1, const int* __restrict__ d1,
                                   const int* __restrict__ s2, const int* __restrict__ d2,
                                   int N, int& src, int& key) {
  if (i < E0)            { src = s0[i];            key = d0[i]; }
  else if (i < E0 + E1)  { src = s1[i - E0];       key = N + d1[i - E0]; }
  else                   { src = s2[i - E0 - E1];  key = 2 * N + d2[i - E0 - E1]; }
}

// ---------- K1: stage (blocks < SB) || prep WbigT (blocks >= SB) -------------
struct StageSmem {
  ushort es_src[CHUNK];
  int    es_key[CHUNK];
  int    lh[NBMAX];
  int    lb[NBMAX];
};

__global__ __launch_bounds__(256, 2)
void stage_prep_kernel(const int* __restrict__ s0, const int* __restrict__ d0,
                       const int* __restrict__ s1, const int* __restrict__ d1,
                       const int* __restrict__ s2, const int* __restrict__ d2,
                       int E0, int E1, int E2,
                       int* __restrict__ bcnt, unsigned* __restrict__ staging,
                       int N, int NB, int SB,
                       const float* __restrict__ W,
                       const float* __restrict__ a_src,
                       const float* __restrict__ a_dst,
                       ushort* __restrict__ WbigT) {
  __shared__ __align__(16) char smem_raw[sizeof(StageSmem)];
  const int t = threadIdx.x;
  if (blockIdx.x >= SB) {
    // ---- prep body ----
    int i = (blockIdx.x - SB) * 256 + t;   // over 448*256
    int c = i >> 8, k = i & 255;
    float v = 0.f;
    if (c < 384) {
      int r = c >> 7, j = c & 127;
      v = W[((size_t)r * 256 + k) * 128 + j];
    } else if (c < 408) {
      int c6 = c - 384, r = c6 >> 3, hh = c6 & 7, hd = hh & 3;
      const float* a = (hh < 4 ? a_src : a_dst) + (r * 4 + hd) * 32;
      const float* wp = W + ((size_t)r * 256 + k) * 128 + hd * 32;
#pragma unroll
      for (int d = 0; d < 32; ++d) v += wp[d] * a[d];
    }
    WbigT[i] = f2bf(v);
    return;
  }
  // ---- stage body ----
  StageSmem& sm = *reinterpret_cast<StageSmem*>(smem_raw);
  for (int k = t; k < NB; k += 256) sm.lh[k] = 0;
  __syncthreads();
  const int Etot = E0 + E1 + E2;
  const int lo = blockIdx.x * CHUNK;
  const int hi = min(lo + CHUNK, Etot);
  const int n = hi - lo;
  for (int i = t; i < n; i += 256) {
    int src, key;
    edge_decode(lo + i, E0, E1, s0, d0, s1, d1, s2, d2, N, src, key);
    sm.es_src[i] = (ushort)src;
    sm.es_key[i] = key;
    atomicAdd(&sm.lh[key >> 9], 1);
  }
  __syncthreads();
  for (int k = t; k < NB; k += 256) {
    int v = sm.lh[k];
    sm.lb[k] = v ? (k * CAP + atomicAdd(&bcnt[k], v)) : 0;
    sm.lh[k] = 0;
  }
  __syncthreads();
  for (int i = t; i < n; i += 256) {
    int key = sm.es_key[i];
    int b = key >> 9;
    int pos = sm.lb[b] + atomicAdd(&sm.lh[b], 1);
    if (pos < (b + 1) * CAP)   // overflow guard (never hit for uniform dst)
      staging[pos] = ((unsigned)(key & 511) << 16) | (unsigned)sm.es_src[i];
  }
}

// ---------- K2: sort (blocks < NB) || gemm (blocks >= NB) --------------------
// sort: single-pass LDS counting sort per bucket (256 thr, 2 keys/thread)
// gemm: [M,256]x[256,448] 32x32x16 bf16; hall REL-MAJOR [3][N][128]
struct GemmSmem {
  ushort As[64][40];
  ushort Bs[448][40];
};
struct SortSmem {
  unsigned es[CAP];      // 40KB bucket slice
  int cnt[KB];
  int cur[KB];
  int wsum[4];
};

__global__ __launch_bounds__(256, 2)
void sort_gemm_kernel(const unsigned* __restrict__ staging, const int* __restrict__ bcnt,
                      int* __restrict__ offs, int* __restrict__ ends,
                      ushort* __restrict__ srt, int n3, int NB,
                      const float* __restrict__ x, const ushort* __restrict__ WT,
                      ushort* __restrict__ hall, float* __restrict__ al, int M) {
  __shared__ __align__(16) char smem_raw[sizeof(SortSmem) > sizeof(GemmSmem)
                                             ? sizeof(SortSmem) : sizeof(GemmSmem)];
  const int t = threadIdx.x;

  if (blockIdx.x < NB) {
    // ================= SORT body =================
    SortSmem& sm = *reinterpret_cast<SortSmem*>(smem_raw);
    const int b = blockIdx.x;
    const int base = b * KB;
    const int lo = b * CAP;
    const int m = min(bcnt[b], CAP);
    sm.cnt[t] = 0;
    sm.cnt[t + 256] = 0;
    __syncthreads();
    for (int i = t; i < m; i += 256) {
      unsigned p = staging[lo + i];
      sm.es[i] = p;
      atomicAdd(&sm.cnt[p >> 16], 1);
    }
    __syncthreads();
    // exclusive scan over 512 keys, 2 per thread
    const int lane = t & 63, wid = t >> 6;
    int c0 = sm.cnt[2 * t], c1 = sm.cnt[2 * t + 1];
    int v = c0 + c1;
    int sv = v;
#pragma unroll
    for (int d = 1; d < 64; d <<= 1) {
      int u = __shfl_up(sv, d);
      if (lane >= d) sv += u;
    }
    if (lane == 63) sm.wsum[wid] = sv;
    __syncthreads();
    if (t < 4) {
      int ws = sm.wsum[t];
#pragma unroll
      for (int d = 1; d < 4; d <<= 1) {
        int u = __shfl_up(ws, d);
        if (t >= d) ws += u;
      }
      sm.wsum[t] = ws;
    }
    __syncthreads();
    int excl = (wid ? sm.wsum[wid - 1] : 0) + sv - v;
    int st0 = lo + excl;
    int st1 = st0 + c0;
    sm.cur[2 * t] = st0;
    sm.cur[2 * t + 1] = st1;
    if (base + 2 * t < n3) {
      offs[base + 2 * t] = st0;
      ends[base + 2 * t] = st0 + c0;
    }
    if (base + 2 * t + 1 < n3) {
      offs[base + 2 * t + 1] = st1;
      ends[base + 2 * t + 1] = st1 + c1;
    }
    __syncthreads();
    for (int i = t; i < m; i += 256) {
      unsigned p = sm.es[i];
      int pos = atomicAdd(&sm.cur[p >> 16], 1);
      srt[pos] = (ushort)(p & 0xffffu);
    }
  } else {
    // ================= GEMM body =================
    GemmSmem& sm = *reinterpret_cast<GemmSmem*>(smem_raw);
    const int bm = (blockIdx.x - NB) * 64;
    const int l = t & 63;
    const int w = t >> 6;
    const int wm = (w >> 1) * 32;
    const int wn = (w & 1) * 224;
    const int lr31 = l & 31;
    const int kg = (l >> 5) * 8;

    f32x16 acc[7];
#pragma unroll
    for (int j = 0; j < 7; ++j)
#pragma unroll
      for (int r = 0; r < 16; ++r) acc[j][r] = 0.f;

    for (int k0 = 0; k0 < 256; k0 += 32) {
      {
        int row = t >> 2, seg = t & 3;
        int grow = bm + row;
        float4 v0 = make_float4(0.f, 0.f, 0.f, 0.f), v1 = v0;
        if (grow < M) {
          const float* xp = x + (size_t)grow * 256 + k0 + seg * 8;
          v0 = *(const float4*)xp;
          v1 = *(const float4*)(xp + 4);
        }
        uint4 pk;
        pk.x = (unsigned)f2bf(v0.x) | ((unsigned)f2bf(v0.y) << 16);
        pk.y = (unsigned)f2bf(v0.z) | ((unsigned)f2bf(v0.w) << 16);
        pk.z = (unsigned)f2bf(v1.x) | ((unsigned)f2bf(v1.y) << 16);
        pk.w = (unsigned)f2bf(v1.z) | ((unsigned)f2bf(v1.w) << 16);
        *(uint4*)&sm.As[row][seg * 8] = pk;
      }
#pragma unroll
      for (int p = 0; p < 7; ++p) {
        int idx = p * 256 + t;
        int nrow = idx >> 2, ch = idx & 3;
        *(uint4*)&sm.Bs[nrow][ch * 8] =
            *(const uint4*)(WT + (size_t)nrow * 256 + k0 + ch * 8);
      }
      __syncthreads();
#pragma unroll
      for (int kk = 0; kk < 32; kk += 16) {
        bf16x8 af = *(bf16x8*)&sm.As[wm + lr31][kk + kg];
#pragma unroll
        for (int j = 0; j < 7; ++j) {
          bf16x8 bf = *(bf16x8*)&sm.Bs[wn + j * 32 + lr31][kk + kg];
          acc[j] = __builtin_amdgcn_mfma_f32_32x32x16_bf16(af, bf, acc[j], 0, 0, 0);
        }
      }
      __syncthreads();
    }

#pragma unroll
    for (int j = 0; j < 7; ++j) {
      int gcol = wn + j * 32 + lr31;
#pragma unroll
      for (int r = 0; r < 16; ++r) {
        int grow = bm + wm + (l >> 5) * 4 + (r & 3) + 8 * (r >> 2);
        if (grow >= M) continue;
        float c = acc[j][r];
        if (gcol < 384) {
          int rel = gcol >> 7, jj = gcol & 127;
          hall[((size_t)rel * M + grow) * 128 + jj] = f2bf(c);
        } else if (gcol < 408) {
          int c6 = gcol - 384, rr = c6 >> 3, hh = c6 & 7;
          al[(((size_t)(hh < 4 ? 0 : 3) + rr) * M + grow) * 4 + (hh & 3)] = c;
        }
      }
    }
  }
}

// ---------- K3: fused softmax+gather, 4 edges x 16 feature-lanes per wave ----
__global__ __launch_bounds__(128)
void gat_fused_kernel(const ushort* __restrict__ srt, const int* __restrict__ offs,
                      const int* __restrict__ ends,
                      const ushort* __restrict__ hall,
                      const float* __restrict__ al,
                      const float* __restrict__ bias,
                      float* __restrict__ out, int N) {
  const int d = blockIdx.x;
  const int t = threadIdx.x;
  const int w = t >> 6;       // wave 0/1
  const int l = t & 63;
  const int eg = l >> 4;      // edge slot 0..3
  const int fl = l & 15;      // feature slot
  const int h = fl >> 2;      // head

  __shared__ float slab[3][2][16][9];   // rel, wave, fl, {r0..r7, dl}

#pragma unroll
  for (int rel = 0; rel < 3; ++rel) {
    const int key = rel * N + d;
    const int start = offs[key];
    const int dend = ends[key];
    const float* alS = al + (size_t)rel * N * 4;
    const ushort* hrel = hall + (size_t)rel * N * 128;
    const float ald = al[((size_t)(3 + rel) * N + d) * 4 + h];
    float r0 = 0.f, r1 = 0.f, r2 = 0.f, r3 = 0.f;
    float r4 = 0.f, r5 = 0.f, r6 = 0.f, r7 = 0.f;
    float dl = 0.f;
#pragma unroll 2
    for (int e = start + w * 4 + eg; e < dend; e += 8) {
      int s = srt[e];
      float a = alS[(size_t)s * 4 + h] + ald;
      a = fmaxf(a, NEG_SLOPE * a);     // leaky relu
      float ex = __expf(a);
      dl += ex;
      uint4 u = *(const uint4*)(hrel + (size_t)s * 128 + fl * 8);
      r0 += __uint_as_float(u.x << 16) * ex;
      r1 += __uint_as_float(u.x & 0xffff0000u) * ex;
      r2 += __uint_as_float(u.y << 16) * ex;
      r3 += __uint_as_float(u.y & 0xffff0000u) * ex;
      r4 += __uint_as_float(u.z << 16) * ex;
      r5 += __uint_as_float(u.z & 0xffff0000u) * ex;
      r6 += __uint_as_float(u.w << 16) * ex;
      r7 += __uint_as_float(u.w & 0xffff0000u) * ex;
    }
    r0 += __shfl_xor(r0, 16); r0 += __shfl_xor(r0, 32);
    r1 += __shfl_xor(r1, 16); r1 += __shfl_xor(r1, 32);
    r2 += __shfl_xor(r2, 16); r2 += __shfl_xor(r2, 32);
    r3 += __shfl_xor(r3, 16); r3 += __shfl_xor(r3, 32);
    r4 += __shfl_xor(r4, 16); r4 += __shfl_xor(r4, 32);
    r5 += __shfl_xor(r5, 16); r5 += __shfl_xor(r5, 32);
    r6 += __shfl_xor(r6, 16); r6 += __shfl_xor(r6, 32);
    r7 += __shfl_xor(r7, 16); r7 += __shfl_xor(r7, 32);
    dl += __shfl_xor(dl, 16); dl += __shfl_xor(dl, 32);
    if (l < 16) {
      slab[rel][w][fl][0] = r0; slab[rel][w][fl][1] = r1;
      slab[rel][w][fl][2] = r2; slab[rel][w][fl][3] = r3;
      slab[rel][w][fl][4] = r4; slab[rel][w][fl][5] = r5;
      slab[rel][w][fl][6] = r6; slab[rel][w][fl][7] = r7;
      slab[rel][w][fl][8] = dl;
    }
  }
  __syncthreads();
  {
    int fl2 = t >> 3, k = t & 7;
    int f = fl2 * 8 + k;
    float o = bias[f] + bias[128 + f] + bias[256 + f];
#pragma unroll
    for (int rel = 0; rel < 3; ++rel) {
      float D = slab[rel][0][fl2][8] + slab[rel][1][fl2][8];
      float R = slab[rel][0][fl2][k] + slab[rel][1][fl2][k];
      o += R / (D + 1e-16f);
    }
    out[(size_t)d * 128 + f] = o;
  }
}

extern "C" void kernel_launch(void* const* d_in, const int* in_sizes, int n_in,
                              void* d_out, int out_size, void* d_ws, size_t ws_size,
                              hipStream_t stream) {
  const float* x     = (const float*)d_in[0];
  const int*   ei[3] = {(const int*)d_in[1], (const int*)d_in[2], (const int*)d_in[3]};
  const float* W     = (const float*)d_in[4];
  const float* a_src = (const float*)d_in[5];
  const float* a_dst = (const float*)d_in[6];
  const float* bias  = (const float*)d_in[7];

  const int Fin = 256;
  const int N = in_sizes[0] / Fin;
  const int E0 = in_sizes[1] / 2, E1 = in_sizes[2] / 2, E2 = in_sizes[3] / 2;
  const int Etot = E0 + E1 + E2;
  const int n3 = 3 * N;
  const int NB = (n3 + KB - 1) / KB;          // 512-key buckets
  const int GB = (N + 63) / 64;               // gemm blocks
  const int SB = (Etot + CHUNK - 1) / CHUNK;  // stage blocks

  float* out = (float*)d_out;

  // ws layout
  char* p = (char*)d_ws;
  ushort*   WbigT   = (ushort*)p;    p += (size_t)448 * 256 * 2;
  ushort*   hall    = (ushort*)p;    p += (size_t)N * 384 * 2;
  float*    al      = (float*)p;     p += (size_t)6 * N * 4 * 4;
  unsigned* staging = (unsigned*)p;  p += (size_t)NBMAX * CAP * 4;
  ushort*   srt     = (ushort*)p;    p += (size_t)NBMAX * CAP * 2;
  int*      offs    = (int*)p;       p += (size_t)n3 * 4;
  int*      ends    = (int*)p;       p += (size_t)n3 * 4;
  int*      bcnt    = (int*)p;       p += NBMAX * 4;

  // zero bucket counters (stage runs in K1 now; can't self-zero race-free)
  hipMemsetAsync(bcnt, 0, NBMAX * sizeof(int), stream);

  // K1: stage (long pole, blocks first) || prep WbigT
  stage_prep_kernel<<<SB + 448, 256, 0, stream>>>(
      ei[0], ei[0] + E0, ei[1], ei[1] + E1, ei[2], ei[2] + E2,
      E0, E1, E2, bcnt, staging, N, NB, SB,
      W, a_src, a_dst, WbigT);

  // K2: sort (blocks first, overlaps gemm bulk) || gemm
  sort_gemm_kernel<<<NB + GB, 256, 0, stream>>>(
      staging, bcnt, offs, ends, srt, n3, NB,
      x, WbigT, hall, al, N);

  // K3: fused softmax + gather + bias, one block per dst row
  gat_fused_kernel<<<N, 128, 0, stream>>>(srt, offs, ends, hall, al, bias, out, N);
}